// Round 3
// baseline (622.964 us; speedup 1.0000x reference)
//
#include <hip/hip_runtime.h>
#include <hip/hip_bf16.h>

#define BATCH 1024
#define DIM 512
#define NCLS 100000
#define SCALE 30.0f
#define MARGIN 0.4f
#define BM 1024                      /* full batch per block (W-stationary) */
#define BN 64
#define BK 32
#define KSTEPS (DIM / BK)            /* 16 */
#define NT ((NCLS + BN - 1) / BN)    /* 1563 col tiles */

typedef __bf16 bf16x8 __attribute__((ext_vector_type(8)));
typedef __bf16 bf16x4 __attribute__((ext_vector_type(4)));
typedef float f32x4 __attribute__((ext_vector_type(4)));

// ---------------- kernel 1: row-normalize x, emit bf16 ----------------
__global__ __launch_bounds__(256) void k_norm(const float* __restrict__ x,
                                              __bf16* __restrict__ xb) {
    int row  = blockIdx.x * 4 + (threadIdx.x >> 6);
    int lane = threadIdx.x & 63;
    const float* xr = x + (size_t)row * DIM;
    float4 v0 = *reinterpret_cast<const float4*>(xr + lane * 4);
    float4 v1 = *reinterpret_cast<const float4*>(xr + 256 + lane * 4);
    float ss = v0.x*v0.x + v0.y*v0.y + v0.z*v0.z + v0.w*v0.w
             + v1.x*v1.x + v1.y*v1.y + v1.z*v1.z + v1.w*v1.w;
#pragma unroll
    for (int m = 1; m < 64; m <<= 1) ss += __shfl_xor(ss, m);
    float inv = 1.0f / fmaxf(sqrtf(ss), 1e-12f);
    bf16x4 o0 = { (__bf16)(v0.x*inv), (__bf16)(v0.y*inv), (__bf16)(v0.z*inv), (__bf16)(v0.w*inv) };
    bf16x4 o1 = { (__bf16)(v1.x*inv), (__bf16)(v1.y*inv), (__bf16)(v1.z*inv), (__bf16)(v1.w*inv) };
    *reinterpret_cast<bf16x4*>(xb + (size_t)row * DIM + lane * 4)       = o0;
    *reinterpret_cast<bf16x4*>(xb + (size_t)row * DIM + 256 + lane * 4) = o1;
}

// ------- kernel 2: W-stationary fused GEMM + masked exp row-partials -------
// grid = NT blocks; block ct owns cols [ct*64, ct*64+64) for ALL 1024 rows.
// W read exactly once from HBM. x (1 MB bf16) is L2-resident: A-fragments are
// loaded global->reg directly. Only the 4 KB B tile goes through LDS
// (double-buffered, fp32->bf16 convert hidden under MFMA).
__global__ __launch_bounds__(512) void k_main(const __bf16* __restrict__ xb,
                                              const float* __restrict__ W,
                                              const int* __restrict__ lab32,
                                              float* __restrict__ part,
                                              float* __restrict__ tgt) {
    const int ct      = blockIdx.x;
    const int colBase = ct * BN;
    const int tid     = threadIdx.x;
    const int wid     = tid >> 6;        // 0..7
    const int lane    = tid & 63;
    const int wrow    = wid * 128;       // wave's row base

    // B tile: [buf][kgroup][col][8 k-elems] -> ds_read_b128 / ds_write_b128
    // both conflict-free by construction (contiguous 16B granules per lane).
    __shared__ __align__(16) __bf16 Bs[2][4][BN][8];   // 8 KB
    __shared__ int slab[BATCH];                        // 4 KB
    __shared__ int sflag;

    // ---- label width detect (int64 vs int32) + load all 1024 labels ----
    if (tid < 64) {
        int o = 0;
        for (int i = lane; i < 512; i += 64) o |= lab32[2 * i + 1];
#pragma unroll
        for (int m = 1; m < 64; m <<= 1) o |= __shfl_xor(o, m);
        if (lane == 0) sflag = o;
    }
    __syncthreads();
    const bool is64 = (sflag == 0);
    for (int i = tid; i < BATCH; i += 512) slab[i] = is64 ? lab32[2 * i] : lab32[i];

    f32x4 acc[8][4];
#pragma unroll
    for (int m = 0; m < 8; m++)
#pragma unroll
        for (int n = 0; n < 4; n++) acc[m][n] = (f32x4){0.f, 0.f, 0.f, 0.f};

    // A addressing: frag m covers rows wrow+m*16+(lane&15), k = (lane>>4)*8..+7
    const char* aBase = (const char*)xb
                      + (size_t)(wrow + (lane & 15)) * (DIM * 2)
                      + (lane >> 4) * 16;

    auto loadA = [&](int t, bf16x8* a) {
        const char* p = aBase + t * (BK * 2);
#pragma unroll
        for (int m = 0; m < 8; m++)
            a[m] = *reinterpret_cast<const bf16x8*>(p + m * 16 * (DIM * 2));
    };

    // B staging: 256 threads each move one 16B granule (col c, kgroup kg)
    const int skg = tid >> 6;        // 0..3 (valid when tid<256)
    const int sc  = tid & 63;
    const int sgc = colBase + sc;
    const bool sact = (tid < 256) && (sgc < NCLS);
    const float* wBase = W + (size_t)sgc * DIM + skg * 8;

    auto stageLoad = [&](int t, float4& f0, float4& f1) {
        if (sact) {
            const float* p = wBase + t * BK;
            f0 = *reinterpret_cast<const float4*>(p);
            f1 = *reinterpret_cast<const float4*>(p + 4);
        } else {
            f0 = make_float4(0.f, 0.f, 0.f, 0.f);
            f1 = f0;
        }
    };
    auto stageWrite = [&](int buf, const float4& f0, const float4& f1) {
        if (tid < 256) {
            bf16x8 h = { (__bf16)f0.x, (__bf16)f0.y, (__bf16)f0.z, (__bf16)f0.w,
                         (__bf16)f1.x, (__bf16)f1.y, (__bf16)f1.z, (__bf16)f1.w };
            *reinterpret_cast<bf16x8*>(&Bs[buf][skg][sc][0]) = h;
        }
    };

    bf16x8 aA[8], aB[8];

    // prologue
    loadA(0, aA);
    {
        float4 f0, f1;
        stageLoad(0, f0, f1);
        stageWrite(0, f0, f1);
    }
    __syncthreads();

    auto iter = [&](int t, bf16x8* aC, bf16x8* aN) {
        const int cur = t & 1;
        float4 f0, f1;
        if (t + 1 < KSTEPS) {
            stageLoad(t + 1, f0, f1);   // fp32 B loads in flight during MFMA
            loadA(t + 1, aN);           // next A frags in flight during MFMA
        }
        bf16x8 b[4];
#pragma unroll
        for (int n = 0; n < 4; n++)
            b[n] = *reinterpret_cast<const bf16x8*>(&Bs[cur][lane >> 4][n * 16 + (lane & 15)][0]);
#pragma unroll
        for (int m = 0; m < 8; m++)
#pragma unroll
            for (int n = 0; n < 4; n++)
                acc[m][n] = __builtin_amdgcn_mfma_f32_16x16x32_bf16(aC[m], b[n], acc[m][n], 0, 0, 0);
        if (t + 1 < KSTEPS) stageWrite(cur ^ 1, f0, f1);
        __syncthreads();
    };

#pragma unroll
    for (int th = 0; th < KSTEPS / 2; th++) {
        iter(2 * th,     aA, aB);
        iter(2 * th + 1, aB, aA);
    }

    // ---- epilogue: target logit + masked exp row-partials ----
#pragma unroll
    for (int m = 0; m < 8; m++) {
#pragma unroll
        for (int r = 0; r < 4; r++) {
            int trow = wrow + m * 16 + (lane >> 4) * 4 + r;
            int lb = slab[trow];
            float s = 0.f;
#pragma unroll
            for (int n = 0; n < 4; n++) {
                int gcol = colBase + n * 16 + (lane & 15);
                float v = acc[m][n][r];
                if (gcol == lb) tgt[trow] = v;
                if (gcol < NCLS && gcol != lb) s += __expf(SCALE * v);
            }
#pragma unroll
            for (int mm = 1; mm < 16; mm <<= 1) s += __shfl_xor(s, mm);
            if ((lane & 15) == 0) part[(size_t)trow * NT + ct] = s;
        }
    }
}

// ---------------- kernel 3: per-row reduce + loss term ----------------
__global__ __launch_bounds__(256) void k_row(const float* __restrict__ part,
                                             const float* __restrict__ tgt,
                                             float* __restrict__ Lrow) {
    int row = blockIdx.x;
    int tid = threadIdx.x;
    float s = 0.f;
    for (int t = tid; t < NT; t += 256) s += part[(size_t)row * NT + t];
#pragma unroll
    for (int m = 1; m < 64; m <<= 1) s += __shfl_xor(s, m);
    __shared__ float red[4];
    if ((tid & 63) == 0) red[tid >> 6] = s;
    __syncthreads();
    if (tid == 0) {
        float excl = red[0] + red[1] + red[2] + red[3];
        float num = SCALE * (tgt[row] - MARGIN);
        float den = __expf(num) + excl;
        Lrow[row] = num - logf(den);
    }
}

// ---------------- kernel 4: mean ----------------
__global__ __launch_bounds__(1024) void k_final(const float* __restrict__ Lrow,
                                                float* __restrict__ out) {
    int tid = threadIdx.x;
    float v = Lrow[tid];
#pragma unroll
    for (int m = 1; m < 64; m <<= 1) v += __shfl_xor(v, m);
    __shared__ float red[16];
    if ((tid & 63) == 0) red[tid >> 6] = v;
    __syncthreads();
    if (tid == 0) {
        float s = 0.f;
#pragma unroll
        for (int i = 0; i < 16; i++) s += red[i];
        out[0] = -s / (float)BATCH;
    }
}

extern "C" void kernel_launch(void* const* d_in, const int* in_sizes, int n_in,
                              void* d_out, int out_size, void* d_ws, size_t ws_size,
                              hipStream_t stream) {
    const float* x   = (const float*)d_in[0];
    const int*   lab = (const int*)d_in[1];
    const float* W   = (const float*)d_in[2];
    float* out = (float*)d_out;

    char* ws = (char*)d_ws;
    __bf16* xb  = (__bf16*)ws;                                   // 1 MiB
    float*  part = (float*)(ws + (1 << 20));                     // 1024*NT*4 = 6.4 MB
    float*  tgt  = (float*)(ws + (1 << 20) + (size_t)BATCH * NT * 4);
    float*  Lrow = tgt + BATCH;

    k_norm <<<BATCH / 4, 256, 0, stream>>>(x, xb);
    k_main <<<NT,        512, 0, stream>>>(xb, W, lab, part, tgt);
    k_row  <<<BATCH,     256, 0, stream>>>(part, tgt, Lrow);
    k_final<<<1,        1024, 0, stream>>>(Lrow, out);
}

// Round 5
// 613.317 us; speedup vs baseline: 1.0157x; 1.0157x over previous
//
#include <hip/hip_runtime.h>
#include <hip/hip_bf16.h>

#define BATCH 1024
#define DIM 512
#define NCLS 100000
#define SCALE 30.0f
#define MARGIN 0.4f
#define BM 128
#define BN 64
#define BK 64
#define KSTEPS (DIM / BK)            /* 8 */
#define NT ((NCLS + BN - 1) / BN)    /* 1563 col tiles */
#define GRID_MAIN (8 * 8 * 196)      /* 12544; ct = (idx&7)+8*(idx>>6) covers 0..1567 */

typedef __bf16 bf16x8 __attribute__((ext_vector_type(8)));
typedef __bf16 bf16x4 __attribute__((ext_vector_type(4)));
typedef float f32x4 __attribute__((ext_vector_type(4)));

// ---------------- kernel 1: row-normalize x, emit bf16 ----------------
__global__ __launch_bounds__(256) void k_norm(const float* __restrict__ x,
                                              __bf16* __restrict__ xb) {
    int row  = blockIdx.x * 4 + (threadIdx.x >> 6);
    int lane = threadIdx.x & 63;
    const float* xr = x + (size_t)row * DIM;
    float4 v0 = *reinterpret_cast<const float4*>(xr + lane * 4);
    float4 v1 = *reinterpret_cast<const float4*>(xr + 256 + lane * 4);
    float ss = v0.x*v0.x + v0.y*v0.y + v0.z*v0.z + v0.w*v0.w
             + v1.x*v1.x + v1.y*v1.y + v1.z*v1.z + v1.w*v1.w;
#pragma unroll
    for (int m = 1; m < 64; m <<= 1) ss += __shfl_xor(ss, m);
    float inv = 1.0f / fmaxf(sqrtf(ss), 1e-12f);
    bf16x4 o0 = { (__bf16)(v0.x*inv), (__bf16)(v0.y*inv), (__bf16)(v0.z*inv), (__bf16)(v0.w*inv) };
    bf16x4 o1 = { (__bf16)(v1.x*inv), (__bf16)(v1.y*inv), (__bf16)(v1.z*inv), (__bf16)(v1.w*inv) };
    *reinterpret_cast<bf16x4*>(xb + (size_t)row * DIM + lane * 4)       = o0;
    *reinterpret_cast<bf16x4*>(xb + (size_t)row * DIM + 256 + lane * 4) = o1;
}

// ------- kernel 2: fused GEMM + masked exp row-partials -------
// Round-2 tile structure (good MLP) + XCD-aligned block swizzle: the 8
// row-blocks sharing W-tile ct all get idx%8 == ct%8 -> same XCD L2, so W
// crosses HBM once. B double-buffered (reg prefetch during MFMA); A direct
// L2->reg prefetch (xb is 1 MB, resident in every XCD's L2).
__global__ __launch_bounds__(256) void k_main(const __bf16* __restrict__ xb,
                                              const float* __restrict__ W,
                                              const int* __restrict__ lab32,
                                              float* __restrict__ part,
                                              float* __restrict__ tgt) {
    const int idx = blockIdx.x;
    const int ct  = (idx & 7) + ((idx >> 6) << 3);
    if (ct >= NT) return;
    const int rt  = (idx >> 3) & 7;
    const int colBase = ct * BN;
    const int rowBase = rt * BM;
    const int tid  = threadIdx.x;
    const int wid  = tid >> 6;
    const int lane = tid & 63;

    // B tile: [buf][kgranule(8)][col(64)][8 bf16] -> 16B granules; write
    // (lane==col, 16B consecutive) and read (16 consecutive granules per
    // lane-group) are both at the conflict-free floor.
    __shared__ __align__(16) __bf16 Bs[2][8][BN][8];   // 16 KB
    __shared__ int slab[BM];
    __shared__ int sflag;

    // ---- label width detect (int64 vs int32) ----
    if (tid < 64) {
        int o = 0;
        for (int i = lane; i < 512; i += 64) o |= lab32[2 * i + 1];
#pragma unroll
        for (int m = 1; m < 64; m <<= 1) o |= __shfl_xor(o, m);
        if (lane == 0) sflag = o;
    }
    __syncthreads();
    const bool is64 = (sflag == 0);
    if (tid < BM) slab[tid] = is64 ? lab32[2 * (rowBase + tid)] : lab32[rowBase + tid];

    f32x4 acc[2][4];
#pragma unroll
    for (int m = 0; m < 2; m++)
#pragma unroll
        for (int n = 0; n < 4; n++) acc[m][n] = (f32x4){0.f, 0.f, 0.f, 0.f};

    // A fragment base: frag(m,ks) at rows rowBase+wid*32+m*16+(lane&15),
    // k = t*64 + ks*32 + (lane>>4)*8
    const char* aB = (const char*)xb
                   + (size_t)(rowBase + wid * 32 + (lane & 15)) * (DIM * 2)
                   + (lane >> 4) * 16;

    // B staging: thread = (col = tid&63, kq = tid>>6); 4 float4 per step
    const int scol = tid & 63;
    const int skq  = tid >> 6;
    const int sgc  = colBase + scol;
    const bool sok = (sgc < NCLS);
    const float* wB = W + (size_t)(sok ? sgc : 0) * DIM + skq * 16;

    auto LDA = [&](int t, bf16x8* a) {
#pragma unroll
        for (int ks = 0; ks < 2; ks++)
#pragma unroll
            for (int m = 0; m < 2; m++)
                a[ks * 2 + m] = *reinterpret_cast<const bf16x8*>(
                    aB + (size_t)m * 16 * (DIM * 2) + ks * 64 + t * (BK * 2));
    };
    auto LDB = [&](int t, float4* f) {
#pragma unroll
        for (int i = 0; i < 4; i++)
            f[i] = sok ? *reinterpret_cast<const float4*>(wB + t * BK + i * 4)
                       : make_float4(0.f, 0.f, 0.f, 0.f);
    };
    auto STB = [&](int buf, const float4* f) {
        bf16x8 h0 = { (__bf16)f[0].x, (__bf16)f[0].y, (__bf16)f[0].z, (__bf16)f[0].w,
                      (__bf16)f[1].x, (__bf16)f[1].y, (__bf16)f[1].z, (__bf16)f[1].w };
        bf16x8 h1 = { (__bf16)f[2].x, (__bf16)f[2].y, (__bf16)f[2].z, (__bf16)f[2].w,
                      (__bf16)f[3].x, (__bf16)f[3].y, (__bf16)f[3].z, (__bf16)f[3].w };
        *reinterpret_cast<bf16x8*>(&Bs[buf][skq * 2][scol][0])     = h0;
        *reinterpret_cast<bf16x8*>(&Bs[buf][skq * 2 + 1][scol][0]) = h1;
    };
    auto CMP = [&](int buf, const bf16x8* a) {
#pragma unroll
        for (int ks = 0; ks < 2; ks++)
#pragma unroll
            for (int n = 0; n < 4; n++) {
                bf16x8 b = *reinterpret_cast<const bf16x8*>(
                    &Bs[buf][ks * 4 + (lane >> 4)][n * 16 + (lane & 15)][0]);
                acc[0][n] = __builtin_amdgcn_mfma_f32_16x16x32_bf16(a[ks * 2 + 0], b, acc[0][n], 0, 0, 0);
                acc[1][n] = __builtin_amdgcn_mfma_f32_16x16x32_bf16(a[ks * 2 + 1], b, acc[1][n], 0, 0, 0);
            }
    };

    bf16x8 a0[4], a1[4];
    float4 f0[4], f1[4];

    LDA(0, a0); LDB(0, f0); STB(0, f0);
    __syncthreads();
#pragma unroll
    for (int th = 0; th < KSTEPS / 2; th++) {
        const int t = 2 * th;
        LDB(t + 1, f1);          // B loads in flight across the MFMA cluster
        LDA(t + 1, a1);
        CMP(0, a0);              // compute buf0 while t+1 streams in
        STB(1, f1);              // vmcnt waits only for f1 (a1 stays in flight)
        __syncthreads();
        if (th < KSTEPS / 2 - 1) { LDB(t + 2, f0); LDA(t + 2, a0); }
        CMP(1, a1);
        if (th < KSTEPS / 2 - 1) STB(0, f0);
        __syncthreads();
    }

    // ---- epilogue: target logit + masked exp row-partials ----
#pragma unroll
    for (int m = 0; m < 2; m++) {
#pragma unroll
        for (int r = 0; r < 4; r++) {
            int trow = wid * 32 + m * 16 + (lane >> 4) * 4 + r;
            int grow = rowBase + trow;
            int lb = slab[trow];
            float s = 0.f;
#pragma unroll
            for (int n = 0; n < 4; n++) {
                int gcol = colBase + n * 16 + (lane & 15);
                float v = acc[m][n][r];
                if (gcol == lb) tgt[grow] = v;
                if (gcol < NCLS && gcol != lb) s += __expf(SCALE * v);
            }
#pragma unroll
            for (int mm = 1; mm < 16; mm <<= 1) s += __shfl_xor(s, mm);
            if ((lane & 15) == 0) part[(size_t)grow * NT + ct] = s;
        }
    }
}

// ---------------- kernel 3: per-row reduce + loss term ----------------
__global__ __launch_bounds__(256) void k_row(const float* __restrict__ part,
                                             const float* __restrict__ tgt,
                                             float* __restrict__ Lrow) {
    int row = blockIdx.x;
    int tid = threadIdx.x;
    float s = 0.f;
    for (int t = tid; t < NT; t += 256) s += part[(size_t)row * NT + t];
#pragma unroll
    for (int m = 1; m < 64; m <<= 1) s += __shfl_xor(s, m);
    __shared__ float red[4];
    if ((tid & 63) == 0) red[tid >> 6] = s;
    __syncthreads();
    if (tid == 0) {
        float excl = red[0] + red[1] + red[2] + red[3];
        float num = SCALE * (tgt[row] - MARGIN);
        float den = __expf(num) + excl;
        Lrow[row] = num - logf(den);
    }
}

// ---------------- kernel 4: mean ----------------
__global__ __launch_bounds__(1024) void k_final(const float* __restrict__ Lrow,
                                                float* __restrict__ out) {
    int tid = threadIdx.x;
    float v = Lrow[tid];
#pragma unroll
    for (int m = 1; m < 64; m <<= 1) v += __shfl_xor(v, m);
    __shared__ float red[16];
    if ((tid & 63) == 0) red[tid >> 6] = v;
    __syncthreads();
    if (tid == 0) {
        float s = 0.f;
#pragma unroll
        for (int i = 0; i < 16; i++) s += red[i];
        out[0] = -s / (float)BATCH;
    }
}

extern "C" void kernel_launch(void* const* d_in, const int* in_sizes, int n_in,
                              void* d_out, int out_size, void* d_ws, size_t ws_size,
                              hipStream_t stream) {
    const float* x   = (const float*)d_in[0];
    const int*   lab = (const int*)d_in[1];
    const float* W   = (const float*)d_in[2];
    float* out = (float*)d_out;

    char* ws = (char*)d_ws;
    __bf16* xb  = (__bf16*)ws;                                   // 1 MiB
    float*  part = (float*)(ws + (1 << 20));                     // 1024*NT*4 = 6.4 MB
    float*  tgt  = (float*)(ws + (1 << 20) + (size_t)BATCH * NT * 4);
    float*  Lrow = tgt + BATCH;

    k_norm <<<BATCH / 4, 256, 0, stream>>>(x, xb);
    k_main <<<GRID_MAIN, 256, 0, stream>>>(xb, W, lab, part, tgt);
    k_row  <<<BATCH,     256, 0, stream>>>(part, tgt, Lrow);
    k_final<<<1,        1024, 0, stream>>>(Lrow, out);
}

// Round 7
// 493.869 us; speedup vs baseline: 1.2614x; 1.2419x over previous
//
#include <hip/hip_runtime.h>
#include <hip/hip_bf16.h>

#define BATCH 1024
#define DIM 512
#define NCLS 100000
#define SCALE 30.0f
#define MARGIN 0.4f

typedef __bf16 bf16x8 __attribute__((ext_vector_type(8)));
typedef __bf16 bf16x4 __attribute__((ext_vector_type(4)));
typedef float f32x4 __attribute__((ext_vector_type(4)));

/* fallback (round-5) tile params */
#define BM 128
#define BN 64
#define BK 64
#define KSTEPS (DIM / BK)
#define NT ((NCLS + BN - 1) / BN)        /* 1563 */
#define GRID_MAIN (8 * 8 * 196)

/* glds path params */
#define BM2 128
#define BN2 128
#define BK2 64
#define KS2 (DIM / BK2)                  /* 8 */
#define NT2 ((NCLS + BN2 - 1) / BN2)     /* 782 */
#define PART_W2 (NT2 * 2)                /* 1564 */
#define GRID2 (98 * 64)                  /* ct=(idx&7)+8*(idx>>6) covers 0..783 */

__device__ __forceinline__ void glds16(const void* g, void* l) {
    __builtin_amdgcn_global_load_lds(
        (const __attribute__((address_space(1))) void*)g,
        (__attribute__((address_space(3))) void*)l, 16, 0, 0);
}

// ---------------- kernel 1: row-normalize x, emit bf16 ----------------
__global__ __launch_bounds__(256) void k_norm(const float* __restrict__ x,
                                              __bf16* __restrict__ xb) {
    int row  = blockIdx.x * 4 + (threadIdx.x >> 6);
    int lane = threadIdx.x & 63;
    const float* xr = x + (size_t)row * DIM;
    float4 v0 = *reinterpret_cast<const float4*>(xr + lane * 4);
    float4 v1 = *reinterpret_cast<const float4*>(xr + 256 + lane * 4);
    float ss = v0.x*v0.x + v0.y*v0.y + v0.z*v0.z + v0.w*v0.w
             + v1.x*v1.x + v1.y*v1.y + v1.z*v1.z + v1.w*v1.w;
#pragma unroll
    for (int m = 1; m < 64; m <<= 1) ss += __shfl_xor(ss, m);
    float inv = 1.0f / fmaxf(sqrtf(ss), 1e-12f);
    bf16x4 o0 = { (__bf16)(v0.x*inv), (__bf16)(v0.y*inv), (__bf16)(v0.z*inv), (__bf16)(v0.w*inv) };
    bf16x4 o1 = { (__bf16)(v1.x*inv), (__bf16)(v1.y*inv), (__bf16)(v1.z*inv), (__bf16)(v1.w*inv) };
    *reinterpret_cast<bf16x4*>(xb + (size_t)row * DIM + lane * 4)       = o0;
    *reinterpret_cast<bf16x4*>(xb + (size_t)row * DIM + 256 + lane * 4) = o1;
}

// ---------------- W fp32 -> bf16 streaming convert ----------------
__global__ __launch_bounds__(256) void k_wconv(const float* __restrict__ W,
                                               __bf16* __restrict__ Wb) {
    size_t i0 = (size_t)blockIdx.x * 256 + threadIdx.x;
    const size_t n8 = (size_t)NCLS * DIM / 8;
    for (size_t e = i0; e < n8; e += (size_t)gridDim.x * 256) {
        const float4* p = reinterpret_cast<const float4*>(W + e * 8);
        float4 v0 = p[0], v1 = p[1];
        bf16x8 h = { (__bf16)v0.x, (__bf16)v0.y, (__bf16)v0.z, (__bf16)v0.w,
                     (__bf16)v1.x, (__bf16)v1.y, (__bf16)v1.z, (__bf16)v1.w };
        *reinterpret_cast<bf16x8*>(Wb + e * 8) = h;
    }
}

// ------- kernel 2 (glds path): m97-structure GEMM + fused epilogue -------
// 128x128 tile, BK=64, 4 waves (2x2), 4x4 acc/wave. A and B both staged
// via global_load_lds width=16 (linear LDS dest, XOR-pre-swizzled SOURCE
// addresses so ds_read_b128 is conflict-free). part stored [ct2][row]
// (coalesced block-contiguous writes).
__global__ __launch_bounds__(256) void k_main2(const __bf16* __restrict__ xb,
                                               const __bf16* __restrict__ Wb,
                                               const int* __restrict__ lab32,
                                               float* __restrict__ part,
                                               float* __restrict__ tgt) {
    const int idx = blockIdx.x;
    const int ct  = (idx & 7) + ((idx >> 6) << 3);
    if (ct >= NT2) return;
    const int rt  = (idx >> 3) & 7;
    const int colBase = ct * BN2;
    const int rowBase = rt * BM2;
    const int tid = threadIdx.x;
    const int wid = tid >> 6, lane = tid & 63;
    const int wr = wid >> 1, wc = wid & 1;

    __shared__ __align__(16) __bf16 As[2][BM2 * BK2];   /* 2 x 16 KB */
    __shared__ __align__(16) __bf16 Bs[2][BN2 * BK2];   /* 2 x 16 KB */
    __shared__ int slab[BM2];
    __shared__ int sflag;

    // ---- label width detect (int64 vs int32) ----
    if (tid < 64) {
        int o = 0;
        for (int i = lane; i < 512; i += 64) o |= lab32[2 * i + 1];
#pragma unroll
        for (int m = 1; m < 64; m <<= 1) o |= __shfl_xor(o, m);
        if (lane == 0) sflag = o;
    }
    __syncthreads();
    const bool is64 = (sflag == 0);
    if (tid < BM2) slab[tid] = is64 ? lab32[2 * (rowBase + tid)] : lab32[rowBase + tid];

    // staging geometry: slot s = i*256 + wid*64 + lane; r = s>>3, g = s&7;
    // source granule pre-swizzled: g ^ (r&7). LDS dest is linear slot*16.
    size_t aoff[4], boff[4];
    int dst[4];
#pragma unroll
    for (int i = 0; i < 4; i++) {
        int s = i * 256 + wid * 64 + lane;
        int r = s >> 3, g = s & 7;
        int gs = g ^ (r & 7);
        aoff[i] = (size_t)(rowBase + r) * (DIM * 2) + gs * 16;
        int c = colBase + r; if (c >= NCLS) c = 0;     /* clamp tail */
        boff[i] = (size_t)c * (DIM * 2) + gs * 16;
        dst[i] = (i * 256 + wid * 64) * 16;            /* wave-uniform */
    }

    auto STAGE = [&](int buf, int t) {
        const char* aG = (const char*)xb + t * (BK2 * 2);
        const char* bG = (const char*)Wb + t * (BK2 * 2);
        char* aL = (char*)&As[buf][0];
        char* bL = (char*)&Bs[buf][0];
#pragma unroll
        for (int i = 0; i < 4; i++) glds16(aG + aoff[i], aL + dst[i]);
#pragma unroll
        for (int i = 0; i < 4; i++) glds16(bG + boff[i], bL + dst[i]);
    };

    // frag read byte-offsets (t-independent)
    int aAddr[4][2], bAddr[4][2];
#pragma unroll
    for (int m = 0; m < 4; m++)
#pragma unroll
        for (int kq = 0; kq < 2; kq++) {
            int gA = kq * 4 + (lane >> 4);
            int rA = wr * 64 + m * 16 + (lane & 15);
            aAddr[m][kq] = (rA * 8 + (gA ^ (rA & 7))) * 16;
            int rB = wc * 64 + m * 16 + (lane & 15);
            bAddr[m][kq] = (rB * 8 + (gA ^ (rB & 7))) * 16;
        }

    f32x4 acc[4][4];
#pragma unroll
    for (int m = 0; m < 4; m++)
#pragma unroll
        for (int n = 0; n < 4; n++) acc[m][n] = (f32x4){0.f, 0.f, 0.f, 0.f};

    STAGE(0, 0);
    __syncthreads();
#pragma unroll
    for (int t = 0; t < KS2; t++) {
        const int cur = t & 1;
        if (t + 1 < KS2) STAGE(cur ^ 1, t + 1);
        const char* aT = (const char*)&As[cur][0];
        const char* bT = (const char*)&Bs[cur][0];
#pragma unroll
        for (int kq = 0; kq < 2; kq++) {
            bf16x8 a[4], b[4];
#pragma unroll
            for (int m = 0; m < 4; m++) a[m] = *(const bf16x8*)(aT + aAddr[m][kq]);
#pragma unroll
            for (int n = 0; n < 4; n++) b[n] = *(const bf16x8*)(bT + bAddr[n][kq]);
#pragma unroll
            for (int m = 0; m < 4; m++)
#pragma unroll
                for (int n = 0; n < 4; n++)
                    acc[m][n] = __builtin_amdgcn_mfma_f32_16x16x32_bf16(a[m], b[n], acc[m][n], 0, 0, 0);
        }
        __syncthreads();
    }

    // ---- epilogue: target logit + masked exp row-partials (coalesced) ----
#pragma unroll
    for (int m = 0; m < 4; m++) {
#pragma unroll
        for (int j = 0; j < 4; j++) {
            int trow = wr * 64 + m * 16 + (lane >> 4) * 4 + j;
            int grow = rowBase + trow;
            int lb = slab[trow];
            float s = 0.f;
#pragma unroll
            for (int n = 0; n < 4; n++) {
                int gcol = colBase + wc * 64 + n * 16 + (lane & 15);
                float v = acc[m][n][j];
                if (gcol == lb) tgt[grow] = v;
                if (gcol < NCLS && gcol != lb) s += __expf(SCALE * v);
            }
#pragma unroll
            for (int mm = 1; mm < 16; mm <<= 1) s += __shfl_xor(s, mm);
            if ((lane & 15) == 0) part[(size_t)(ct * 2 + wc) * BATCH + grow] = s;
        }
    }
}

// ------- kernel 2 (fallback, round-5 structure; part transposed) -------
__global__ __launch_bounds__(256) void k_main(const __bf16* __restrict__ xb,
                                              const float* __restrict__ W,
                                              const int* __restrict__ lab32,
                                              float* __restrict__ part,
                                              float* __restrict__ tgt) {
    const int idx = blockIdx.x;
    const int ct  = (idx & 7) + ((idx >> 6) << 3);
    if (ct >= NT) return;
    const int rt  = (idx >> 3) & 7;
    const int colBase = ct * BN;
    const int rowBase = rt * BM;
    const int tid  = threadIdx.x;
    const int wid  = tid >> 6;
    const int lane = tid & 63;

    __shared__ __align__(16) __bf16 Bs[2][8][BN][8];
    __shared__ int slab[BM];
    __shared__ int sflag;

    if (tid < 64) {
        int o = 0;
        for (int i = lane; i < 512; i += 64) o |= lab32[2 * i + 1];
#pragma unroll
        for (int m = 1; m < 64; m <<= 1) o |= __shfl_xor(o, m);
        if (lane == 0) sflag = o;
    }
    __syncthreads();
    const bool is64 = (sflag == 0);
    if (tid < BM) slab[tid] = is64 ? lab32[2 * (rowBase + tid)] : lab32[rowBase + tid];

    f32x4 acc[2][4];
#pragma unroll
    for (int m = 0; m < 2; m++)
#pragma unroll
        for (int n = 0; n < 4; n++) acc[m][n] = (f32x4){0.f, 0.f, 0.f, 0.f};

    const char* aB = (const char*)xb
                   + (size_t)(rowBase + wid * 32 + (lane & 15)) * (DIM * 2)
                   + (lane >> 4) * 16;
    const int scol = tid & 63;
    const int skq  = tid >> 6;
    const int sgc  = colBase + scol;
    const bool sok = (sgc < NCLS);
    const float* wB = W + (size_t)(sok ? sgc : 0) * DIM + skq * 16;

    auto LDA = [&](int t, bf16x8* a) {
#pragma unroll
        for (int ks = 0; ks < 2; ks++)
#pragma unroll
            for (int m = 0; m < 2; m++)
                a[ks * 2 + m] = *reinterpret_cast<const bf16x8*>(
                    aB + (size_t)m * 16 * (DIM * 2) + ks * 64 + t * (BK * 2));
    };
    auto LDB = [&](int t, float4* f) {
#pragma unroll
        for (int i = 0; i < 4; i++)
            f[i] = sok ? *reinterpret_cast<const float4*>(wB + t * BK + i * 4)
                       : make_float4(0.f, 0.f, 0.f, 0.f);
    };
    auto STB = [&](int buf, const float4* f) {
        bf16x8 h0 = { (__bf16)f[0].x, (__bf16)f[0].y, (__bf16)f[0].z, (__bf16)f[0].w,
                      (__bf16)f[1].x, (__bf16)f[1].y, (__bf16)f[1].z, (__bf16)f[1].w };
        bf16x8 h1 = { (__bf16)f[2].x, (__bf16)f[2].y, (__bf16)f[2].z, (__bf16)f[2].w,
                      (__bf16)f[3].x, (__bf16)f[3].y, (__bf16)f[3].z, (__bf16)f[3].w };
        *reinterpret_cast<bf16x8*>(&Bs[buf][skq * 2][scol][0])     = h0;
        *reinterpret_cast<bf16x8*>(&Bs[buf][skq * 2 + 1][scol][0]) = h1;
    };
    auto CMP = [&](int buf, const bf16x8* a) {
#pragma unroll
        for (int ks = 0; ks < 2; ks++)
#pragma unroll
            for (int n = 0; n < 4; n++) {
                bf16x8 b = *reinterpret_cast<const bf16x8*>(
                    &Bs[buf][ks * 4 + (lane >> 4)][n * 16 + (lane & 15)][0]);
                acc[0][n] = __builtin_amdgcn_mfma_f32_16x16x32_bf16(a[ks * 2 + 0], b, acc[0][n], 0, 0, 0);
                acc[1][n] = __builtin_amdgcn_mfma_f32_16x16x32_bf16(a[ks * 2 + 1], b, acc[1][n], 0, 0, 0);
            }
    };

    bf16x8 a0[4], a1[4];
    float4 f0[4], f1[4];
    LDA(0, a0); LDB(0, f0); STB(0, f0);
    __syncthreads();
#pragma unroll
    for (int th = 0; th < KSTEPS / 2; th++) {
        const int t = 2 * th;
        LDB(t + 1, f1);
        LDA(t + 1, a1);
        CMP(0, a0);
        STB(1, f1);
        __syncthreads();
        if (th < KSTEPS / 2 - 1) { LDB(t + 2, f0); LDA(t + 2, a0); }
        CMP(1, a1);
        if (th < KSTEPS / 2 - 1) STB(0, f0);
        __syncthreads();
    }

#pragma unroll
    for (int m = 0; m < 2; m++) {
#pragma unroll
        for (int r = 0; r < 4; r++) {
            int trow = wid * 32 + m * 16 + (lane >> 4) * 4 + r;
            int grow = rowBase + trow;
            int lb = slab[trow];
            float s = 0.f;
#pragma unroll
            for (int n = 0; n < 4; n++) {
                int gcol = colBase + n * 16 + (lane & 15);
                float v = acc[m][n][r];
                if (gcol == lb) tgt[grow] = v;
                if (gcol < NCLS && gcol != lb) s += __expf(SCALE * v);
            }
#pragma unroll
            for (int mm = 1; mm < 16; mm <<= 1) s += __shfl_xor(s, mm);
            if ((lane & 15) == 0) part[(size_t)ct * BATCH + grow] = s;
        }
    }
}

// --------- kernel 3: transposed-part reduce + loss term (16 rows/block) ---------
__global__ __launch_bounds__(256) void k_row(const float* __restrict__ part,
                                             const float* __restrict__ tgt,
                                             float* __restrict__ Lrow, int ntp) {
    int rowBase = blockIdx.x * 16;
    int tid = threadIdx.x;
    int r = tid & 15, ci = tid >> 4;
    float s = 0.f;
    for (int t = ci; t < ntp; t += 16)
        s += part[(size_t)t * BATCH + rowBase + r];
    __shared__ float red[16][17];
    red[ci][r] = s;
    __syncthreads();
    if (tid < 16) {
        float tot = 0.f;
#pragma unroll
        for (int i = 0; i < 16; i++) tot += red[i][tid];
        int row = rowBase + tid;
        float num = SCALE * (tgt[row] - MARGIN);
        Lrow[row] = num - logf(__expf(num) + tot);
    }
}

// ---------------- kernel 4: mean ----------------
__global__ __launch_bounds__(1024) void k_final(const float* __restrict__ Lrow,
                                                float* __restrict__ out) {
    int tid = threadIdx.x;
    float v = Lrow[tid];
#pragma unroll
    for (int m = 1; m < 64; m <<= 1) v += __shfl_xor(v, m);
    __shared__ float red[16];
    if ((tid & 63) == 0) red[tid >> 6] = v;
    __syncthreads();
    if (tid == 0) {
        float s = 0.f;
#pragma unroll
        for (int i = 0; i < 16; i++) s += red[i];
        out[0] = -s / (float)BATCH;
    }
}

extern "C" void kernel_launch(void* const* d_in, const int* in_sizes, int n_in,
                              void* d_out, int out_size, void* d_ws, size_t ws_size,
                              hipStream_t stream) {
    const float* x   = (const float*)d_in[0];
    const int*   lab = (const int*)d_in[1];
    const float* W   = (const float*)d_in[2];
    float* out = (float*)d_out;

    char* ws = (char*)d_ws;
    __bf16* xb   = (__bf16*)ws;                        /* @0,    1 MB   */
    float*  part = (float*)(ws + (1 << 20));           /* @1MB,  6.4 MB */
    float*  tgt  = (float*)(ws + (8 << 20));           /* @8MB,  4 KB   */
    float*  Lrow = (float*)(ws + (8 << 20) + (64 << 10));
    __bf16* Wb   = (__bf16*)(ws + (16 << 20));         /* @16MB, 102.4 MB */
    const size_t NEED = ((size_t)16 << 20) + (size_t)NCLS * DIM * 2;

    k_norm<<<BATCH / 4, 256, 0, stream>>>(x, xb);
    if (ws_size >= NEED) {
        k_wconv<<<2048, 256, 0, stream>>>(W, Wb);
        k_main2<<<GRID2, 256, 0, stream>>>(xb, Wb, lab, part, tgt);
        k_row<<<BATCH / 16, 256, 0, stream>>>(part, tgt, Lrow, PART_W2);
    } else {
        k_main<<<GRID_MAIN, 256, 0, stream>>>(xb, W, lab, part, tgt);
        k_row<<<BATCH / 16, 256, 0, stream>>>(part, tgt, Lrow, NT);
    }
    k_final<<<1, 1024, 0, stream>>>(Lrow, out);
}